// Round 5
// baseline (161.204 us; speedup 1.0000x reference)
//
#include <hip/hip_runtime.h>
#include <hip/hip_bf16.h>

// Spalize: out0[k,c,h,w] = img[c,h,w] * (mask[h,w]==k); out1 = mask (as float).
// K=50, C=3, H=W=512. 157 MB output -> HBM-write-bound.
// R0-R2: three structures (1 wave/SIMD; split-K; linear sweep) ALL ~157us
// total => kernel ~60us (2.6 TB/s) regardless of pattern/occupancy.
// Harness poison fill does 6.6 TB/s on the same bytes -> write path, not DRAM,
// is the gap. R3/R4: non-temporal stores (global_store_dwordx4 nt) to bypass
// L2 write-allocate for the 157 MB stream; L2 stays dedicated to the 4 MB
// mask/img re-read working set. NOTE: builtin requires native ext_vector_type,
// not HIP's float4 class (R3 compile fail).

#define K  50
#define C  3
#define H  512
#define W  512
#define HW (H * W)                 // 262144
#define OUT0 (K * C * HW)          // 39,321,600 floats
#define OUT_TOTAL (OUT0 + HW)      // 39,583,744 floats
#define BLOCK 256

typedef float vfloat4 __attribute__((ext_vector_type(4)));
typedef int   vint4   __attribute__((ext_vector_type(4)));

__global__ __launch_bounds__(BLOCK) void spalize_kernel(
    const float* __restrict__ img,   // [C,H,W]
    const int*   __restrict__ mask,  // [H,W] int32
    float*       __restrict__ out)   // [K,C,H,W] then [H,W] mask-as-float
{
    const int tid = blockIdx.x * BLOCK + threadIdx.x;
    const int f = tid * 4;           // flat output float index

    if (f < OUT0) {
        const int plane = f >> 18;          // f / HW  (wave-uniform)
        const int p     = f & (HW - 1);     // pixel index
        const int k     = (plane * 0x5556) >> 16;  // plane / 3 (plane < 150)
        const int c     = plane - k * 3;

        const vint4   m = *reinterpret_cast<const vint4*>(mask + p);
        const vfloat4 a = *reinterpret_cast<const vfloat4*>(img + c * HW + p);

        vfloat4 o;
        o.x = (m.x == k) ? a.x : 0.0f;
        o.y = (m.y == k) ? a.y : 0.0f;
        o.z = (m.z == k) ? a.z : 0.0f;
        o.w = (m.w == k) ? a.w : 0.0f;
        __builtin_nontemporal_store(o, reinterpret_cast<vfloat4*>(out + f));
    } else {
        const int p = f - OUT0;             // mask pass-through
        const vint4 m = *reinterpret_cast<const vint4*>(mask + p);
        vfloat4 mf;
        mf.x = (float)m.x; mf.y = (float)m.y;
        mf.z = (float)m.z; mf.w = (float)m.w;
        __builtin_nontemporal_store(mf, reinterpret_cast<vfloat4*>(out + f));
    }
}

extern "C" void kernel_launch(void* const* d_in, const int* in_sizes, int n_in,
                              void* d_out, int out_size, void* d_ws, size_t ws_size,
                              hipStream_t stream) {
    const float* img  = (const float*)d_in[0];
    const int*   mask = (const int*)d_in[1];
    float*       out  = (float*)d_out;

    const int nthreads = OUT_TOTAL / 4;          // 9,895,936
    const int grid = nthreads / BLOCK;           // 38,656 blocks (exact)
    spalize_kernel<<<grid, BLOCK, 0, stream>>>(img, mask, out);
}